// Round 3
// baseline (69.293 us; speedup 1.0000x reference)
//
#include <hip/hip_runtime.h>
#include <hip/hip_bf16.h>

#define B_N   8192
#define DIN   512
#define DH    512
#define NACT  18
#define NTASK 16
#define BM    64
#define NT_MAX 144

typedef __attribute__((ext_vector_type(8))) short  short8v;
typedef __attribute__((ext_vector_type(8))) unsigned short ushort8v;
typedef __attribute__((ext_vector_type(4))) unsigned short ushort4v;
typedef __attribute__((ext_vector_type(4))) float  float4v;
typedef __attribute__((ext_vector_type(2))) float  float2v;
typedef __attribute__((ext_vector_type(2))) unsigned int uint2v;

typedef const __attribute__((address_space(1))) void* gas_ptr;
typedef __attribute__((address_space(3))) void* las_ptr;

__device__ __forceinline__ unsigned short f2bf(float f) {
  union { float f; unsigned int u; } c; c.f = f;
  unsigned int u = c.u;
  u += 0x7fffu + ((u >> 16) & 1u);   // RNE
  return (unsigned short)(u >> 16);
}

// ============================================================ prep kernel
// block 0: histogram + tile list + stable-ish scatter (sort rows by task)
// blocks 1..1024: W1 [t][k][n] f32 -> W1T [t][n][k] bf16
// blocks 1025..1152: W2 [t][k][j] f32 -> W2T [t][j(32pad)][k] bf16
__global__ __launch_bounds__(256) void k_prep(
    const float* __restrict__ W1, const float* __restrict__ W2,
    const int* __restrict__ task_id,
    short* __restrict__ W1T, short* __restrict__ W2T,
    int* __restrict__ tl_task, int* __restrict__ tl_row0, int* __restrict__ tl_cnt,
    int* __restrict__ ntile, int* __restrict__ rowidx) {
  __shared__ int s_cnt[NTASK];
  __shared__ int s_cur[NTASK];
  __shared__ int s_tl[NT_MAX * 3 + 1];
  __shared__ __align__(16) short ldsA[64][72];
  __shared__ float ldsB[64 * 19];
  int tid = threadIdx.x;
  int bx = blockIdx.x;

  if (bx == 0) {
    // ---- histogram + sort
    if (tid < NTASK) s_cnt[tid] = 0;
    __syncthreads();
    for (int i = tid; i < B_N; i += 256) atomicAdd(&s_cnt[task_id[i]], 1);
    __syncthreads();
    if (tid == 0) {
      int acc = 0, nt = 0;
      for (int t = 0; t < NTASK; ++t) {
        int c = s_cnt[t];
        s_cur[t] = acc;
        for (int r = 0; r < c; r += BM) {
          s_tl[nt * 3 + 0] = t;
          s_tl[nt * 3 + 1] = acc + r;
          s_tl[nt * 3 + 2] = (c - r < BM) ? (c - r) : BM;
          ++nt;
        }
        acc += c;
      }
      s_tl[NT_MAX * 3] = nt;
    }
    __syncthreads();
    int nt = s_tl[NT_MAX * 3];
    if (tid == 0) *ntile = nt;
    for (int i = tid; i < nt; i += 256) {
      tl_task[i] = s_tl[i * 3 + 0];
      tl_row0[i] = s_tl[i * 3 + 1];
      tl_cnt[i]  = s_tl[i * 3 + 2];
    }
    for (int i = tid; i < B_N; i += 256) {
      int t = task_id[i];
      int pos = atomicAdd(&s_cur[t], 1);
      rowidx[pos] = i;
    }
  } else if (bx <= 1024) {
    // ---- W1 transpose 64x64 tile
    int u = bx - 1;
    int nb = u & 7, kb = (u >> 3) & 7, t = u >> 6;
    int r   = tid >> 2;            // k-row 0..63
    int c16 = (tid & 3) << 4;      // n-col 0,16,32,48
    const float* src = W1 + ((size_t)t * DIN + (size_t)(kb * 64 + r)) * DH + nb * 64 + c16;
#pragma unroll
    for (int p = 0; p < 4; ++p) {
      float4v v = *(const float4v*)(src + p * 4);
#pragma unroll
      for (int i = 0; i < 4; ++i) ldsA[c16 + p * 4 + i][r] = (short)f2bf(v[i]);
    }
    __syncthreads();
    int n = tid >> 2, k16 = (tid & 3) << 4;
    short* dst = W1T + ((size_t)t * DH + nb * 64 + n) * DIN + kb * 64 + k16;
    *(ushort8v*)dst       = *(ushort8v*)&ldsA[n][k16];
    *(ushort8v*)(dst + 8) = *(ushort8v*)&ldsA[n][k16 + 8];
  } else {
    // ---- W2 transpose + pad: [t][k][18] -> [t][32][512] bf16
    int u = bx - 1025;
    int t = u >> 3, k0 = (u & 7) * 64;
    for (int i = tid; i < 64 * NACT; i += 256) {
      int kk = i / NACT, j = i - kk * NACT;
      ldsB[kk * 19 + j] = W2[((size_t)t * DIN + k0 + kk) * NACT + j];
    }
    __syncthreads();
    for (int o = tid; o < 32 * 64; o += 256) {
      int j = o >> 6, kk = o & 63;
      float val = (j < NACT) ? ldsB[kk * 19 + j] : 0.0f;
      W2T[((size_t)t * 32 + j) * DIN + k0 + kk] = (short)f2bf(val);
    }
  }
}

// ============================================================ fused kernel
// One block per 64-row task tile:
//   GEMM1 (swapped): acc[n][m] = W1T[n][k] x xT[k][m]   (K-loop, dbuf)
//   epilogue: +b1, relu, bf16 -> h LDS [64 m][512 n] (chunk-XOR swizzled)
//   GEMM2: logits[m][j] = h[m][k] x W2T[j][k]^T  (per-wave K-slice, ds_add reduce)
//   softmax + entropy -> out
__global__ __launch_bounds__(256, 1) void k_fused(
    const float* __restrict__ x, const float* __restrict__ bias1,
    const float* __restrict__ bias2, const int* __restrict__ action,
    const short* __restrict__ W1T, const short* __restrict__ W2T,
    const int* __restrict__ tl_task, const int* __restrict__ tl_row0,
    const int* __restrict__ tl_cnt, const int* __restrict__ ntile,
    const int* __restrict__ rowidx, float* __restrict__ out) {
  __shared__ __align__(16) short sW1[2][2048 * 8];   // 2 x 32 KB, chunk-major
  __shared__ __align__(16) short sA[2][64 * 40];     // 2 x 5 KB, row stride 40 shorts
  __shared__ __align__(16) short hT[64 * 512];       // 64 KB, [m][n] swizzled chunks
  __shared__ float slog[64 * 33];                    // logits accumulator (pad 33)
  __shared__ int s_rows[64];

  int ti = blockIdx.x;
  if (ti >= *ntile) return;
  int task = tl_task[ti], row0 = tl_row0[ti], mcnt = tl_cnt[ti];
  int tid = threadIdx.x, lane = tid & 63, wave = tid >> 6;

  if (tid < 64) {
    int idx = row0 + tid;
    if (idx > B_N - 1) idx = B_N - 1;
    s_rows[tid] = rowidx[idx];
  }
  for (int i = tid; i < 64 * 33; i += 256) slog[i] = 0.0f;
  __syncthreads();

  // staging constants
  int nbase = tid >> 2;                         // W1T row within a 64-row group
  int gsw = (tid & 3) ^ ((nbase >> 1) & 3);     // pre-swizzled source chunk
  const short* w1src = W1T + (size_t)task * DH * DIN + (size_t)nbase * DIN + gsw * 8;
  int arow = tid >> 2, acn = tid & 3;
  const float* xsrc = x + (size_t)s_rows[arow] * DIN + acn * 8;

#define STAGE_W1(buf, k0e)                                             \
  _Pragma("unroll") for (int it = 0; it < 8; ++it) {                   \
    __builtin_amdgcn_global_load_lds(                                  \
        (gas_ptr)(const void*)(w1src + (size_t)it * 64 * DIN + (k0e)), \
        (las_ptr)(void*)(&sW1[buf][(it * 256 + tid) * 8]), 16, 0, 0);  \
  }

  // prologue: stage step 0
  STAGE_W1(0, 0)
  {
    float4v av0 = *(const float4v*)(xsrc);
    float4v av1 = *(const float4v*)(xsrc + 4);
    ushort8v ap;
#pragma unroll
    for (int i = 0; i < 4; ++i) { ap[i] = f2bf(av0[i]); ap[4 + i] = f2bf(av1[i]); }
    *(ushort8v*)&sA[0][arow * 40 + acn * 8] = ap;
  }
  asm volatile("s_waitcnt vmcnt(0)" ::: "memory");
  __syncthreads();

  float4v acc[8][4];
#pragma unroll
  for (int i = 0; i < 8; ++i)
#pragma unroll
    for (int j = 0; j < 4; ++j) acc[i][j] = (float4v)0.0f;

  int nw = wave * 128;    // this wave's n-slice

  for (int step = 0; step < 16; ++step) {
    int p = step & 1;
    int k0n = (step + 1) * 32;
    float4v av0, av1;
    if (step < 15) {
      STAGE_W1(p ^ 1, k0n)
      av0 = *(const float4v*)(xsrc + k0n);
      av1 = *(const float4v*)(xsrc + k0n + 4);
    }
    // fragments from buffer p
    short8v bfr[4];
#pragma unroll
    for (int fn = 0; fn < 4; ++fn) {
      int m = fn * 16 + (lane & 15);
      bfr[fn] = *(const short8v*)&sA[p][m * 40 + (lane >> 4) * 8];
    }
#pragma unroll
    for (int fm = 0; fm < 8; ++fm) {
      int n = nw + fm * 16 + (lane & 15);
      int L = n * 4 + ((lane >> 4) ^ ((n >> 1) & 3));
      short8v afr = *(const short8v*)&sW1[p][L * 8];
#pragma unroll
      for (int fn = 0; fn < 4; ++fn)
        acc[fm][fn] = __builtin_amdgcn_mfma_f32_16x16x32_bf16(afr, bfr[fn], acc[fm][fn], 0, 0, 0);
    }
    if (step < 15) {
      ushort8v ap;
#pragma unroll
      for (int i = 0; i < 4; ++i) { ap[i] = f2bf(av0[i]); ap[4 + i] = f2bf(av1[i]); }
      *(ushort8v*)&sA[p ^ 1][arow * 40 + acn * 8] = ap;
    }
    asm volatile("s_waitcnt vmcnt(0)" ::: "memory");
    __syncthreads();
  }

  // epilogue-1: +bias, relu, bf16 pack, write h[m][n] swizzled (b64 stores)
#pragma unroll
  for (int fm = 0; fm < 8; ++fm) {
    int n0 = nw + fm * 16 + (lane >> 4) * 4;   // 4 consecutive n
    float4v bias = *(const float4v*)(bias1 + task * DH + n0);
#pragma unroll
    for (int fn = 0; fn < 4; ++fn) {
      int m = fn * 16 + (lane & 15);
      float v0 = fmaxf(acc[fm][fn][0] + bias[0], 0.0f);
      float v1 = fmaxf(acc[fm][fn][1] + bias[1], 0.0f);
      float v2 = fmaxf(acc[fm][fn][2] + bias[2], 0.0f);
      float v3 = fmaxf(acc[fm][fn][3] + bias[3], 0.0f);
      uint2v d;
      d[0] = (unsigned)f2bf(v0) | ((unsigned)f2bf(v1) << 16);
      d[1] = (unsigned)f2bf(v2) | ((unsigned)f2bf(v3) << 16);
      int byteaddr = m * 1024 + (((n0 >> 3) ^ (m & 7)) << 4) + ((n0 & 7) << 1);
      *(uint2v*)((char*)hT + byteaddr) = d;
    }
  }
  __syncthreads();

  // GEMM2: per-wave K-slice of 128; logits[m][j] += h[m][k] * W2T[j][k]
  float4v acc2[4][2];
#pragma unroll
  for (int i = 0; i < 4; ++i) { acc2[i][0] = (float4v)0.0f; acc2[i][1] = (float4v)0.0f; }
  const short* w2t = W2T + (size_t)task * 32 * DIN;
#pragma unroll
  for (int ks = 0; ks < 4; ++ks) {
    int kk = wave * 128 + ks * 32;
    short8v b2f[2];
#pragma unroll
    for (int fn = 0; fn < 2; ++fn) {
      int j = fn * 16 + (lane & 15);
      b2f[fn] = *(const short8v*)(w2t + (size_t)j * DIN + kk + (lane >> 4) * 8);
    }
#pragma unroll
    for (int fm = 0; fm < 4; ++fm) {
      int m = fm * 16 + (lane & 15);
      int c = (kk >> 3) + (lane >> 4);
      short8v af = *(const short8v*)((char*)hT + m * 1024 + ((c ^ (m & 7)) << 4));
#pragma unroll
      for (int fn = 0; fn < 2; ++fn)
        acc2[fm][fn] = __builtin_amdgcn_mfma_f32_16x16x32_bf16(af, b2f[fn], acc2[fm][fn], 0, 0, 0);
    }
  }
#pragma unroll
  for (int fm = 0; fm < 4; ++fm)
#pragma unroll
    for (int fn = 0; fn < 2; ++fn)
#pragma unroll
      for (int r = 0; r < 4; ++r) {
        int m = fm * 16 + (lane >> 4) * 4 + r;
        int j = fn * 16 + (lane & 15);
        atomicAdd(&slog[m * 33 + j], acc2[fm][fn][r]);
      }
  __syncthreads();

  // softmax + entropy (one thread per row)
  if (tid < 64 && tid < mcnt) {
    int m = tid, orig = s_rows[m];
    int act = action[orig];
    float lg[NACT];
#pragma unroll
    for (int j = 0; j < NACT; ++j) lg[j] = slog[m * 33 + j] + bias2[task * NACT + j];
    float mx = lg[0];
#pragma unroll
    for (int j = 1; j < NACT; ++j) mx = fmaxf(mx, lg[j]);
    float s1 = 0.0f, s2 = 0.0f, la = 0.0f;
#pragma unroll
    for (int j = 0; j < NACT; ++j) {
      float e = __expf(lg[j] - mx);
      s1 += e; s2 += e * lg[j];
      la = (j == act) ? lg[j] : la;
    }
    float logZ = __logf(s1);
    float2v o;
    o[0] = la - mx - logZ;
    o[1] = (mx + logZ) - s2 / s1;
    *(float2v*)(out + (size_t)orig * 2) = o;
  }
}

// ----------------------------------------------------------------------------
extern "C" void kernel_launch(void* const* d_in, const int* in_sizes, int n_in,
                              void* d_out, int out_size, void* d_ws, size_t ws_size,
                              hipStream_t stream) {
  const float* x       = (const float*)d_in[0];
  const int*   task_id = (const int*)d_in[1];
  const int*   action  = (const int*)d_in[2];
  const float* W1      = (const float*)d_in[3];
  const float* b1      = (const float*)d_in[4];
  const float* W2      = (const float*)d_in[5];
  const float* b2      = (const float*)d_in[6];
  float* out = (float*)d_out;

  char* ws = (char*)d_ws;
  int* tl_task = (int*)ws;                 // 144
  int* tl_row0 = tl_task + NT_MAX;
  int* tl_cnt  = tl_row0 + NT_MAX;
  int* ntile   = tl_cnt + NT_MAX;
  int* rowidx  = (int*)(ws + 4096);        // 8192 ints -> ends 36864
  size_t off = 36864;
  short* W1T = (short*)(ws + off);  off += (size_t)NTASK * DH * DIN * 2;   // 8.39 MB
  short* W2T = (short*)(ws + off);  off += (size_t)NTASK * 32 * DIN * 2;   // 0.52 MB

  k_prep<<<1153, 256, 0, stream>>>(W1, W2, task_id, W1T, W2T,
                                   tl_task, tl_row0, tl_cnt, ntile, rowidx);
  k_fused<<<NT_MAX, 256, 0, stream>>>(x, b1, b2, action, W1T, W2T,
                                      tl_task, tl_row0, tl_cnt, ntile, rowidx, out);
}